// Round 2
// baseline (5460.844 us; speedup 1.0000x reference)
//
#include <hip/hip_runtime.h>
#include <cstdint>

#define NPT   16384
#define BATCH 2
#define MOUT  2048
#define KNBR  64
#define FPS_T 512
#define PPT   (NPT / FPS_T)   // 32 points per thread
#define CAP   2048            // max in-radius candidates buffered per center

// f32(0.2*0.2 computed in double) — must match JAX's weak-scalar cast exactly.
#define R2_F32 0.039999999105930328f

// Exact-order d^2: ((dx*dx + dy*dy) + dz*dz), no FMA contraction — matches
// jnp.sum((a-b)**2, -1) rounding so selection (argmax / radius / top_k) is
// bit-identical to the reference.
__device__ __forceinline__ float d2_exact(float ax, float ay, float az,
                                          float bx, float by, float bz) {
  float dx = __fsub_rn(ax, bx);
  float dy = __fsub_rn(ay, by);
  float dz = __fsub_rn(az, bz);
  return __fadd_rn(__fadd_rn(__fmul_rn(dx, dx), __fmul_rn(dy, dy)),
                   __fmul_rn(dz, dz));
}

// ---------------------------------------------------------------------------
// Kernel 0: transpose weights into ws so MLP columns are contiguous (s_load).
// layout in ws (floats): W1T[64][6] @0, W2T[64][64] @384, W3T[128][64] @4480
// ---------------------------------------------------------------------------
__global__ void prep_kernel(const float* __restrict__ W1,
                            const float* __restrict__ W2,
                            const float* __restrict__ W3,
                            float* __restrict__ ws) {
  int t = threadIdx.x + blockIdx.x * blockDim.x;
  int stride = blockDim.x * gridDim.x;
  for (int idx = t; idx < 64 * 6; idx += stride) {
    int j = idx / 6, i = idx - j * 6;
    ws[idx] = W1[i * 64 + j];
  }
  for (int idx = t; idx < 64 * 64; idx += stride) {
    int j = idx >> 6, i = idx & 63;
    ws[384 + idx] = W2[i * 64 + j];
  }
  for (int idx = t; idx < 128 * 64; idx += stride) {
    int j = idx >> 6, i = idx & 63;
    ws[4480 + idx] = W3[i * 128 + j];
  }
}

// ---------------------------------------------------------------------------
// Kernel 1: farthest point sampling. One block per cloud. All point coords and
// running min-distances live in registers (PPT per thread). Per iteration:
// block argmax via packed u64 (d2_bits<<32 | ~idx) so ties pick lowest index,
// then the owning thread publishes the winner's coords through LDS.
// ---------------------------------------------------------------------------
__global__ __launch_bounds__(FPS_T) void fps_kernel(
    const float* __restrict__ pos, float* __restrict__ centers) {
  const int b = blockIdx.x;
  const float* __restrict__ P = pos + (size_t)b * NPT * 3;
  float* __restrict__ Cout = centers + (size_t)b * MOUT * 3;
  const int t = threadIdx.x;
  const int lane = t & 63;
  const int wid = t >> 6;

  float px[PPT], py[PPT], pz[PPT], mind[PPT];
#pragma unroll
  for (int p = 0; p < PPT; ++p) {
    int g = t + p * FPS_T;
    px[p] = P[g * 3 + 0];
    py[p] = P[g * 3 + 1];
    pz[p] = P[g * 3 + 2];
  }

  __shared__ float qs[3];
  __shared__ unsigned long long wkeys[FPS_T / 64];

  // center 0 is point 0
  float qx = P[0], qy = P[1], qz = P[2];
  if (t == 0) { Cout[0] = qx; Cout[1] = qy; Cout[2] = qz; }

  float bestv = -1.0f;
  unsigned bestg = 0;
#pragma unroll
  for (int p = 0; p < PPT; ++p) {
    int g = t + p * FPS_T;
    float d2 = d2_exact(px[p], py[p], pz[p], qx, qy, qz);
    mind[p] = d2;
    if (d2 > bestv) { bestv = d2; bestg = (unsigned)g; }  // strict > : first (lowest) index wins in-thread
  }

  for (int s = 1; s < MOUT; ++s) {
    // ---- block argmax of mind ----
    unsigned long long key =
        ((unsigned long long)__float_as_uint(bestv) << 32) |
        (unsigned long long)(~bestg);
#pragma unroll
    for (int d = 1; d < 64; d <<= 1) {
      unsigned long long o = __shfl_xor(key, d, 64);
      if (o > key) key = o;
    }
    if (lane == 0) wkeys[wid] = key;
    __syncthreads();
    unsigned long long wk = wkeys[0];
#pragma unroll
    for (int w = 1; w < FPS_T / 64; ++w) {
      unsigned long long o = wkeys[w];
      if (o > wk) wk = o;
    }
    const unsigned gw = ~((unsigned)(wk & 0xFFFFFFFFull));

    // owner thread publishes coords + writes the center
#pragma unroll
    for (int p = 0; p < PPT; ++p) {
      int g = t + p * FPS_T;
      if ((unsigned)g == gw) {
        qs[0] = px[p]; qs[1] = py[p]; qs[2] = pz[p];
        Cout[s * 3 + 0] = px[p];
        Cout[s * 3 + 1] = py[p];
        Cout[s * 3 + 2] = pz[p];
      }
    }
    __syncthreads();
    qx = qs[0]; qy = qs[1]; qz = qs[2];

    // ---- update mind, track next argmax candidate ----
    bestv = -1.0f; bestg = 0;
#pragma unroll
    for (int p = 0; p < PPT; ++p) {
      int g = t + p * FPS_T;
      float d2 = d2_exact(px[p], py[p], pz[p], qx, qy, qz);
      float m = fminf(mind[p], d2);
      mind[p] = m;
      if (m > bestv) { bestv = m; bestg = (unsigned)g; }
    }
  }
}

// ---------------------------------------------------------------------------
// Kernel 2: ball query + K-nearest selection. One block (256 thr) per center.
// Collect in-radius candidates as packed (d2_bits<<32 | idx) in LDS, bitonic
// sort ascending (== top_k of -masked: nearest first, ties -> lower index),
// emit first K indices (or -1) + count.
// ---------------------------------------------------------------------------
__global__ __launch_bounds__(256) void ballq_kernel(
    const float* __restrict__ pos, const float* __restrict__ centers,
    int* __restrict__ nbr, int* __restrict__ ncnt) {
  const int bm = blockIdx.x;        // b*MOUT + m
  const int b = bm >> 11;           // MOUT = 2048
  const int t = threadIdx.x;

  __shared__ unsigned long long keys[CAP];
  __shared__ int cnt;
  if (t == 0) cnt = 0;
  __syncthreads();

  const float cx = centers[(size_t)bm * 3 + 0];
  const float cy = centers[(size_t)bm * 3 + 1];
  const float cz = centers[(size_t)bm * 3 + 2];
  const float* __restrict__ P = pos + (size_t)b * NPT * 3;

  for (int g = t; g < NPT; g += 256) {
    float d2 = d2_exact(cx, cy, cz, P[g * 3 + 0], P[g * 3 + 1], P[g * 3 + 2]);
    if (d2 <= R2_F32) {
      int s = atomicAdd(&cnt, 1);
      if (s < CAP)
        keys[s] = ((unsigned long long)__float_as_uint(d2) << 32) |
                  (unsigned long long)(unsigned)g;
    }
  }
  __syncthreads();

  int C = cnt; if (C > CAP) C = CAP;
  int P2 = 64; while (P2 < C) P2 <<= 1;
  for (int i = C + t; i < P2; i += 256) keys[i] = ~0ULL;
  __syncthreads();

  for (int k = 2; k <= P2; k <<= 1) {
    for (int j = k >> 1; j > 0; j >>= 1) {
      for (int i = t; i < P2; i += 256) {
        int ixj = i ^ j;
        if (ixj > i) {
          unsigned long long a = keys[i], c = keys[ixj];
          bool up = ((i & k) == 0);
          if ((a > c) == up) { keys[i] = c; keys[ixj] = a; }
        }
      }
      __syncthreads();
    }
  }

  if (t < KNBR) {
    int v = (t < C) ? (int)(unsigned)(keys[t] & 0xFFFFFFFFull) : -1;
    nbr[(size_t)bm * KNBR + t] = v;
  }
  if (t == 0) ncnt[bm] = (C < KNBR) ? C : KNBR;
}

// ---------------------------------------------------------------------------
// Kernel 3: per-neighbor MLP + max aggregation. One wave per center, lane =
// neighbor. Weights read column-wise from transposed copies (uniform address
// -> scalar loads), activations h1/h2 fully unrolled into VGPRs (static
// indexing only — rule #20). Cross-lane max via shfl_xor butterfly.
// ---------------------------------------------------------------------------
__global__ __launch_bounds__(256) void mlp_kernel(
    const float* __restrict__ x, const float* __restrict__ pos,
    const float* __restrict__ centers, const int* __restrict__ nbr,
    const int* __restrict__ ncnt, const float* __restrict__ wsw,
    const float* __restrict__ b1, const float* __restrict__ b2,
    const float* __restrict__ b3, float* __restrict__ out) {
  const int lane = threadIdx.x & 63;
  const int bm = blockIdx.x * 4 + (threadIdx.x >> 6);
  const int b = bm >> 11;

  const float* __restrict__ w1t = wsw;          // [64][6]
  const float* __restrict__ w2t = wsw + 384;    // [64][64]
  const float* __restrict__ w3t = wsw + 4480;   // [128][64]

  const int cnt = ncnt[bm];
  const bool valid = lane < cnt;
  int gr = nbr[(size_t)bm * KNBR + lane];
  int g = valid ? gr : 0;

  const float cx = centers[(size_t)bm * 3 + 0];
  const float cy = centers[(size_t)bm * 3 + 1];
  const float cz = centers[(size_t)bm * 3 + 2];
  const float* __restrict__ Pb = pos + (size_t)b * NPT * 3;
  const float* __restrict__ Xb = x + (size_t)b * NPT * 3;

  float f0 = Xb[g * 3 + 0], f1 = Xb[g * 3 + 1], f2 = Xb[g * 3 + 2];
  float f3 = Pb[g * 3 + 0] - cx, f4 = Pb[g * 3 + 1] - cy, f5 = Pb[g * 3 + 2] - cz;

  float h1[64];
#pragma unroll
  for (int j = 0; j < 64; ++j) {
    float a = b1[j];
    a = fmaf(f0, w1t[j * 6 + 0], a);
    a = fmaf(f1, w1t[j * 6 + 1], a);
    a = fmaf(f2, w1t[j * 6 + 2], a);
    a = fmaf(f3, w1t[j * 6 + 3], a);
    a = fmaf(f4, w1t[j * 6 + 4], a);
    a = fmaf(f5, w1t[j * 6 + 5], a);
    h1[j] = fmaxf(a, 0.0f);
  }

  float h2[64];
#pragma unroll
  for (int j = 0; j < 64; ++j) {
    float a = b2[j];
#pragma unroll
    for (int i = 0; i < 64; ++i) a = fmaf(h1[i], w2t[j * 64 + i], a);
    h2[j] = fmaxf(a, 0.0f);
  }

  float* __restrict__ O = out + (size_t)bm * 128;
#pragma unroll
  for (int j = 0; j < 128; ++j) {
    float a = b3[j];
#pragma unroll
    for (int i = 0; i < 64; ++i) a = fmaf(h2[i], w3t[j * 64 + i], a);
    float v = valid ? a : -INFINITY;
#pragma unroll
    for (int d = 1; d < 64; d <<= 1) v = fmaxf(v, __shfl_xor(v, d, 64));
    if (v == -INFINITY) v = 0.0f;  // empty-neighborhood guard (cnt>=1 always, but match ref)
    if (lane == 0) O[j] = v;
  }
}

// ---------------------------------------------------------------------------
extern "C" void kernel_launch(void* const* d_in, const int* in_sizes, int n_in,
                              void* d_out, int out_size, void* d_ws,
                              size_t ws_size, hipStream_t stream) {
  const float* x   = (const float*)d_in[0];
  const float* pos = (const float*)d_in[1];
  const float* W1  = (const float*)d_in[2];
  const float* b1  = (const float*)d_in[3];
  const float* W2  = (const float*)d_in[4];
  const float* b2  = (const float*)d_in[5];
  const float* W3  = (const float*)d_in[6];
  const float* b3  = (const float*)d_in[7];

  float* out     = (float*)d_out;                          // [B, M, 128]
  float* centers = out + (size_t)BATCH * MOUT * 128;       // [B, M, 3]

  float* wsw = (float*)d_ws;                               // 12672 floats
  int* nbr  = (int*)((char*)d_ws + 51200);                 // [B*M, 64]
  int* ncnt = (int*)((char*)d_ws + 51200 + (size_t)BATCH * MOUT * KNBR * 4);

  prep_kernel<<<32, 256, 0, stream>>>(W1, W2, W3, wsw);
  fps_kernel<<<BATCH, FPS_T, 0, stream>>>(pos, centers);
  ballq_kernel<<<BATCH * MOUT, 256, 0, stream>>>(pos, centers, nbr, ncnt);
  mlp_kernel<<<BATCH * MOUT / 4, 256, 0, stream>>>(x, pos, centers, nbr, ncnt,
                                                   wsw, b1, b2, b3, out);
}

// Round 9
// 3383.458 us; speedup vs baseline: 1.6140x; 1.6140x over previous
//
#include <hip/hip_runtime.h>
#include <cstdint>

#define NPT   16384
#define BATCH 2
#define MOUT  2048
#define KNBR  64
#define CAP   2048            // max in-radius candidates buffered per center
#define FPS_T 1024
#define PPT   (NPT / FPS_T)   // 16 points per thread
#define NW    (FPS_T / 64)    // 16 waves

// f32(0.2*0.2 computed in double) — must match JAX's weak-scalar cast exactly.
#define R2_F32 0.039999999105930328f

// Exact-order d^2: ((dx*dx + dy*dy) + dz*dz), no FMA contraction — matches
// jnp.sum((a-b)**2, -1) rounding so selection (argmax / radius / top_k) is
// bit-identical to the reference. (R2 run confirmed: absmax == 0.0)
__device__ __forceinline__ float d2_exact(float ax, float ay, float az,
                                          float bx, float by, float bz) {
  float dx = __fsub_rn(ax, bx);
  float dy = __fsub_rn(ay, by);
  float dz = __fsub_rn(az, bz);
  return __fadd_rn(__fadd_rn(__fmul_rn(dx, dx), __fmul_rn(dy, dy)),
                   __fmul_rn(dz, dz));
}

// ---------------------------------------------------------------------------
// Kernel 0: transpose weights into ws so MLP columns are contiguous.
// layout in ws (floats): W1T[64][6] @0, W2T[64][64] @384, W3T[128][64] @4480
// ---------------------------------------------------------------------------
__global__ void prep_kernel(const float* __restrict__ W1,
                            const float* __restrict__ W2,
                            const float* __restrict__ W3,
                            float* __restrict__ ws) {
  int t = threadIdx.x + blockIdx.x * blockDim.x;
  int stride = blockDim.x * gridDim.x;
  for (int idx = t; idx < 64 * 6; idx += stride) {
    int j = idx / 6, i = idx - j * 6;
    ws[idx] = W1[i * 64 + j];
  }
  for (int idx = t; idx < 64 * 64; idx += stride) {
    int j = idx >> 6, i = idx & 63;
    ws[384 + idx] = W2[i * 64 + j];
  }
  for (int idx = t; idx < 128 * 64; idx += stride) {
    int j = idx >> 6, i = idx & 63;
    ws[4480 + idx] = W3[i * 128 + j];
  }
}

// ---------------------------------------------------------------------------
// Kernel 0b: Morton counting-sort of points into spatially-coherent order.
// One block (512 thr) per cloud. 8x8x8 cells, Morton-coded cell ids.
// Within-cell order is nondeterministic (atomicAdd) — FPS output is invariant
// to it: all reductions are exact max/min keyed on original index oidx.
// ---------------------------------------------------------------------------
__device__ __forceinline__ int morton3_8(int x, int y, int z) {
  int c = 0;
#pragma unroll
  for (int k = 0; k < 3; ++k)
    c |= (((x >> k) & 1) << (3 * k)) | (((y >> k) & 1) << (3 * k + 1)) |
         (((z >> k) & 1) << (3 * k + 2));
  return c;
}

__global__ __launch_bounds__(512) void bin_kernel(
    const float* __restrict__ pos, float* __restrict__ sx,
    float* __restrict__ sy, float* __restrict__ sz, int* __restrict__ soi) {
  const int b = blockIdx.x;
  const int t = threadIdx.x;
  const float* __restrict__ P = pos + (size_t)b * NPT * 3;

  __shared__ int hist[512];
  __shared__ int scan[512];
  __shared__ unsigned short cid[NPT];

  hist[t] = 0;
  __syncthreads();

  for (int p = 0; p < 32; ++p) {
    int g = t + p * 512;
    float x = P[g * 3 + 0], y = P[g * 3 + 1], z = P[g * 3 + 2];
    int ix = (int)(x * 8.0f); ix = ix < 0 ? 0 : (ix > 7 ? 7 : ix);
    int iy = (int)(y * 8.0f); iy = iy < 0 ? 0 : (iy > 7 ? 7 : iy);
    int iz = (int)(z * 8.0f); iz = iz < 0 ? 0 : (iz > 7 ? 7 : iz);
    int c = morton3_8(ix, iy, iz);
    cid[g] = (unsigned short)c;
    atomicAdd(&hist[c], 1);
  }
  __syncthreads();

  // inclusive scan of hist -> scan (Hillis-Steele)
  int cnt = hist[t];
  int v = cnt;
  scan[t] = v;
  __syncthreads();
  for (int off = 1; off < 512; off <<= 1) {
    int add = (t >= off) ? scan[t - off] : 0;
    __syncthreads();
    v += add;
    scan[t] = v;
    __syncthreads();
  }
  // exclusive base as scatter cursor (reuse hist)
  hist[t] = scan[t] - cnt;
  __syncthreads();

  for (int p = 0; p < 32; ++p) {
    int g = t + p * 512;
    int c = cid[g];
    int dst = atomicAdd(&hist[c], 1);
    sx[b * NPT + dst] = P[g * 3 + 0];
    sy[b * NPT + dst] = P[g * 3 + 1];
    sz[b * NPT + dst] = P[g * 3 + 2];
    soi[b * NPT + dst] = g;
  }
}

// ---------------------------------------------------------------------------
// Kernel 1: farthest point sampling with exact AABB pruning.
// One block (1024 thr) per cloud; thread owns 16 Morton-contiguous points in
// registers + their tight AABB. Per iteration:
//   (1) f32 butterfly + LDS reduce of per-thread running max -> gv
//   (2) threads with tm==gv resolve exact argmax tie-break (lowest ORIGINAL
//       index) via LDS atomicMin of (oidx<<14 | t<<4 | slot)
//   (3) owner publishes winner coords; all update mind, skipping the whole
//       thread if dmin2(q, AABB) > tm*1.0001  [conservative: skipped fminf
//       updates are provably identity -> bit-exact; 1e-5 margin >> ~1e-6
//       worst-case accumulated f32 rounding of dmin2 + d2_exact]
// ---------------------------------------------------------------------------
__global__ __launch_bounds__(FPS_T) void fps_kernel(
    const float* __restrict__ pos, const float* __restrict__ sx,
    const float* __restrict__ sy, const float* __restrict__ sz,
    const int* __restrict__ soi, float* __restrict__ centers) {
  const int b = blockIdx.x;
  const int t = threadIdx.x;
  const int lane = t & 63;
  const int wid = t >> 6;
  const float* __restrict__ P = pos + (size_t)b * NPT * 3;
  float* __restrict__ Cout = centers + (size_t)b * MOUT * 3;

  float px[PPT], py[PPT], pz[PPT], mind[PPT];
  int oid[PPT];
  const int base = b * NPT + t * PPT;
#pragma unroll
  for (int p = 0; p < PPT; ++p) {
    px[p] = sx[base + p];
    py[p] = sy[base + p];
    pz[p] = sz[base + p];
    oid[p] = soi[base + p];
  }

  // tight per-thread AABB (exact fmin/fmax of exact coords)
  float lox = px[0], hix = px[0], loy = py[0], hiy = py[0], loz = pz[0], hiz = pz[0];
#pragma unroll
  for (int p = 1; p < PPT; ++p) {
    lox = fminf(lox, px[p]); hix = fmaxf(hix, px[p]);
    loy = fminf(loy, py[p]); hiy = fmaxf(hiy, py[p]);
    loz = fminf(loz, pz[p]); hiz = fmaxf(hiz, pz[p]);
  }

  __shared__ float wmax[NW];
  __shared__ float qs[3];
  __shared__ int owner;

  float qx = P[0], qy = P[1], qz = P[2];
  if (t == 0) {
    Cout[0] = qx; Cout[1] = qy; Cout[2] = qz;
    owner = 0x7fffffff;
  }

  float t0 = -1.0f, t1 = -1.0f;
#pragma unroll
  for (int p = 0; p < PPT; ++p) {
    float d2 = d2_exact(px[p], py[p], pz[p], qx, qy, qz);
    mind[p] = d2;
    if (p & 1) t1 = fmaxf(t1, d2); else t0 = fmaxf(t0, d2);
  }
  float tm = fmaxf(t0, t1);

  for (int s = 1; s < MOUT; ++s) {
    // ---- block max of tm (value only, f32 butterfly + LDS) ----
    float v = tm;
#pragma unroll
    for (int d = 1; d < 64; d <<= 1) v = fmaxf(v, __shfl_xor(v, d, 64));
    if (lane == 0) wmax[wid] = v;
    __syncthreads();  // b1
    float gv = wmax[0];
#pragma unroll
    for (int w = 1; w < NW; ++w) gv = fmaxf(gv, wmax[w]);

    // ---- exact argmax tie-break: lowest original index ----
    if (tm == gv) {
      int cand = 0x7fffffff;
#pragma unroll
      for (int p = 0; p < PPT; ++p)
        if (mind[p] == gv) cand = min(cand, (oid[p] << 14) | (t << 4) | p);
      atomicMin(&owner, cand);
    }
    __syncthreads();  // b2

    // ---- owner publishes winner coords + center ----
    int w = owner;
    if (t == ((w >> 4) & 1023)) {
      int slot = w & 15;
#pragma unroll
      for (int p = 0; p < PPT; ++p)
        if (p == slot) {
          qs[0] = px[p]; qs[1] = py[p]; qs[2] = pz[p];
          Cout[s * 3 + 0] = px[p];
          Cout[s * 3 + 1] = py[p];
          Cout[s * 3 + 2] = pz[p];
        }
    }
    __syncthreads();  // b3
    qx = qs[0]; qy = qs[1]; qz = qs[2];
    if (t == 0) owner = 0x7fffffff;  // safe: next atomicMin is after next b1

    // ---- pruned mind update ----
    float ddx = fmaxf(fmaxf(lox - qx, qx - hix), 0.0f);
    float ddy = fmaxf(fmaxf(loy - qy, qy - hiy), 0.0f);
    float ddz = fmaxf(fmaxf(loz - qz, qz - hiz), 0.0f);
    float dmin2 = ddx * ddx + ddy * ddy + ddz * ddz;
    if (dmin2 <= tm * 1.0001f) {
      float u0 = -1.0f, u1 = -1.0f;
#pragma unroll
      for (int p = 0; p < PPT; ++p) {
        float d2 = d2_exact(px[p], py[p], pz[p], qx, qy, qz);
        float m = fminf(mind[p], d2);
        mind[p] = m;
        if (p & 1) u1 = fmaxf(u1, m); else u0 = fmaxf(u0, m);
      }
      tm = fmaxf(u0, u1);
    }
  }
}

// ---------------------------------------------------------------------------
// Kernel 2: ball query + K-nearest selection. One block (256 thr) per center.
// Collect in-radius candidates as packed (d2_bits<<32 | idx) in LDS, bitonic
// sort ascending (== top_k of -masked: nearest first, ties -> lower index),
// emit first K indices (or -1) + count.
// ---------------------------------------------------------------------------
__global__ __launch_bounds__(256) void ballq_kernel(
    const float* __restrict__ pos, const float* __restrict__ centers,
    int* __restrict__ nbr, int* __restrict__ ncnt) {
  const int bm = blockIdx.x;        // b*MOUT + m
  const int b = bm >> 11;           // MOUT = 2048
  const int t = threadIdx.x;

  __shared__ unsigned long long keys[CAP];
  __shared__ int cnt;
  if (t == 0) cnt = 0;
  __syncthreads();

  const float cx = centers[(size_t)bm * 3 + 0];
  const float cy = centers[(size_t)bm * 3 + 1];
  const float cz = centers[(size_t)bm * 3 + 2];
  const float* __restrict__ P = pos + (size_t)b * NPT * 3;

  for (int g = t; g < NPT; g += 256) {
    float d2 = d2_exact(cx, cy, cz, P[g * 3 + 0], P[g * 3 + 1], P[g * 3 + 2]);
    if (d2 <= R2_F32) {
      int s = atomicAdd(&cnt, 1);
      if (s < CAP)
        keys[s] = ((unsigned long long)__float_as_uint(d2) << 32) |
                  (unsigned long long)(unsigned)g;
    }
  }
  __syncthreads();

  int C = cnt; if (C > CAP) C = CAP;
  int P2 = 64; while (P2 < C) P2 <<= 1;
  for (int i = C + t; i < P2; i += 256) keys[i] = ~0ULL;
  __syncthreads();

  for (int k = 2; k <= P2; k <<= 1) {
    for (int j = k >> 1; j > 0; j >>= 1) {
      for (int i = t; i < P2; i += 256) {
        int ixj = i ^ j;
        if (ixj > i) {
          unsigned long long a = keys[i], c = keys[ixj];
          bool up = ((i & k) == 0);
          if ((a > c) == up) { keys[i] = c; keys[ixj] = a; }
        }
      }
      __syncthreads();
    }
  }

  if (t < KNBR) {
    int v = (t < C) ? (int)(unsigned)(keys[t] & 0xFFFFFFFFull) : -1;
    nbr[(size_t)bm * KNBR + t] = v;
  }
  if (t == 0) ncnt[bm] = (C < KNBR) ? C : KNBR;
}

// ---------------------------------------------------------------------------
// Kernel 3: per-neighbor MLP + max aggregation. One wave per center, lane =
// neighbor. Weights read column-wise from transposed copies (uniform address
// -> scalar loads), activations h1/h2 fully unrolled into VGPRs (static
// indexing only — rule #20). Cross-lane max via shfl_xor butterfly.
// ---------------------------------------------------------------------------
__global__ __launch_bounds__(256) void mlp_kernel(
    const float* __restrict__ x, const float* __restrict__ pos,
    const float* __restrict__ centers, const int* __restrict__ nbr,
    const int* __restrict__ ncnt, const float* __restrict__ wsw,
    const float* __restrict__ b1, const float* __restrict__ b2,
    const float* __restrict__ b3, float* __restrict__ out) {
  const int lane = threadIdx.x & 63;
  const int bm = blockIdx.x * 4 + (threadIdx.x >> 6);
  const int b = bm >> 11;

  const float* __restrict__ w1t = wsw;          // [64][6]
  const float* __restrict__ w2t = wsw + 384;    // [64][64]
  const float* __restrict__ w3t = wsw + 4480;   // [128][64]

  const int cnt = ncnt[bm];
  const bool valid = lane < cnt;
  int gr = nbr[(size_t)bm * KNBR + lane];
  int g = valid ? gr : 0;

  const float cx = centers[(size_t)bm * 3 + 0];
  const float cy = centers[(size_t)bm * 3 + 1];
  const float cz = centers[(size_t)bm * 3 + 2];
  const float* __restrict__ Pb = pos + (size_t)b * NPT * 3;
  const float* __restrict__ Xb = x + (size_t)b * NPT * 3;

  float f0 = Xb[g * 3 + 0], f1 = Xb[g * 3 + 1], f2 = Xb[g * 3 + 2];
  float f3 = Pb[g * 3 + 0] - cx, f4 = Pb[g * 3 + 1] - cy, f5 = Pb[g * 3 + 2] - cz;

  float h1[64];
#pragma unroll
  for (int j = 0; j < 64; ++j) {
    float a = b1[j];
    a = fmaf(f0, w1t[j * 6 + 0], a);
    a = fmaf(f1, w1t[j * 6 + 1], a);
    a = fmaf(f2, w1t[j * 6 + 2], a);
    a = fmaf(f3, w1t[j * 6 + 3], a);
    a = fmaf(f4, w1t[j * 6 + 4], a);
    a = fmaf(f5, w1t[j * 6 + 5], a);
    h1[j] = fmaxf(a, 0.0f);
  }

  float h2[64];
#pragma unroll
  for (int j = 0; j < 64; ++j) {
    float a = b2[j];
#pragma unroll
    for (int i = 0; i < 64; ++i) a = fmaf(h1[i], w2t[j * 64 + i], a);
    h2[j] = fmaxf(a, 0.0f);
  }

  float* __restrict__ O = out + (size_t)bm * 128;
#pragma unroll
  for (int j = 0; j < 128; ++j) {
    float a = b3[j];
#pragma unroll
    for (int i = 0; i < 64; ++i) a = fmaf(h2[i], w3t[j * 64 + i], a);
    float v = valid ? a : -INFINITY;
#pragma unroll
    for (int d = 1; d < 64; d <<= 1) v = fmaxf(v, __shfl_xor(v, d, 64));
    if (v == -INFINITY) v = 0.0f;  // empty-neighborhood guard
    if (lane == 0) O[j] = v;
  }
}

// ---------------------------------------------------------------------------
// ws layout (bytes) — FIXED from R5: ncnt must sit AFTER nbr's full 1 MB
// extent (R5 placed it at 575488, inside nbr [51200, 1099776) -> concurrent
// clobber of cloud-1 neighbor lists <-> ncnt, absmax 0.303).
//   [0, 50688)           transposed weights (12672 floats)
//   [51200, 575488)      sorted sx/sy/sz/soi (4 x 131072) — dead after fps
//   [51200, 1099776)     nbr [B*M*K] ints — written by ballq AFTER fps
//   [1099776, 1116160)   ncnt [B*M] ints
// ---------------------------------------------------------------------------
extern "C" void kernel_launch(void* const* d_in, const int* in_sizes, int n_in,
                              void* d_out, int out_size, void* d_ws,
                              size_t ws_size, hipStream_t stream) {
  const float* x   = (const float*)d_in[0];
  const float* pos = (const float*)d_in[1];
  const float* W1  = (const float*)d_in[2];
  const float* b1  = (const float*)d_in[3];
  const float* W2  = (const float*)d_in[4];
  const float* b2  = (const float*)d_in[5];
  const float* W3  = (const float*)d_in[6];
  const float* b3  = (const float*)d_in[7];

  float* out     = (float*)d_out;                          // [B, M, 128]
  float* centers = out + (size_t)BATCH * MOUT * 128;       // [B, M, 3]

  char* wsb = (char*)d_ws;
  float* wsw = (float*)d_ws;
  float* sx = (float*)(wsb + 51200);
  float* sy = (float*)(wsb + 182272);
  float* sz = (float*)(wsb + 313344);
  int*   soi = (int*)(wsb + 444416);
  int*   nbr = (int*)(wsb + 51200);     // aliases sorted arrays (dead by then)
  int*   ncnt = (int*)(wsb + 51200 + (size_t)BATCH * MOUT * KNBR * 4);

  prep_kernel<<<32, 256, 0, stream>>>(W1, W2, W3, wsw);
  bin_kernel<<<BATCH, 512, 0, stream>>>(pos, sx, sy, sz, soi);
  fps_kernel<<<BATCH, FPS_T, 0, stream>>>(pos, sx, sy, sz, soi, centers);
  ballq_kernel<<<BATCH * MOUT, 256, 0, stream>>>(pos, centers, nbr, ncnt);
  mlp_kernel<<<BATCH * MOUT / 4, 256, 0, stream>>>(x, pos, centers, nbr, ncnt,
                                                   wsw, b1, b2, b3, out);
}